// Round 14
// baseline (55.231 us; speedup 1.0000x reference)
//
#include <hip/hip_runtime.h>
#include <math.h>

// NoisyTopKGating via fp16x2-split MFMA.
// Kernel 2 config: BM=64 rows x 128 cols, K-split=2 (K=1024/block), grid=512,
// 512 threads (8 waves = 2 rg x 4 cg), NBUF=3 x 24KB = 72KB LDS -> 2 blocks/CU
// (16 waves/CU, 4/SIMD). Per-CU traffic identical to the R8 best; TLP doubled.
// Pipeline: global_load_lds staging, stage AFTER barrier (NBUF=3 race-free),
// counted vmcnt(3) steady-state, vmcnt(0) only at the last iteration.
// out layout (f32 flat): weights [N,2] @0, indices-as-float [N,2] @32768, clean [N,64] @65536.
// d_ws: wh (512KB) @0, wl (512KB) @512KB, partials [2][16384][128] f32 (16MB) @1MB.
// Packed W layout (f16 units): [(kc*8 + cg*2 + cf)*512 + lane*8 + j]
//   col = cg*32 + cf*16 + (lane&15),  k = kc*32 + (lane>>4)*8 + j.

constexpr int NROWS = 16384;
constexpr int DDIM  = 2048;
constexpr int EDIM  = 64;
constexpr int BM    = 64;             // rows per block
constexpr int NKS   = 32;             // k-steps of 32 per block (K-half = 1024)
constexpr int IDX_OFF   = NROWS * 2;
constexpr int CLEAN_OFF = NROWS * 4;
constexpr size_t WPACK = 262144;      // f16 elements per packed matrix (128*2048)
constexpr int BUFSZ = 24576;          // x 8KB @0, Bh 8KB @8192, Bl 8KB @16384
constexpr int NBUF  = 3;              // 72KB dynamic LDS -> 2 blocks/CU

typedef _Float16 f16x8 __attribute__((ext_vector_type(8)));
typedef float    f32x4 __attribute__((ext_vector_type(4)));

__device__ __forceinline__ float softplus_f(float z) {
    return fmaxf(z, 0.0f) + log1pf(expf(-fabsf(z)));
}

__device__ __forceinline__ void gload16(const void* g, void* l) {
    __builtin_amdgcn_global_load_lds(
        (const __attribute__((address_space(1))) unsigned int*)g,
        (__attribute__((address_space(3))) unsigned int*)l, 16, 0, 0);
}

// ---------- kernel 1: split + pack weights into frag-ordered hi/lo ----------
__global__ __launch_bounds__(256) void split_w_kernel(
    const float* __restrict__ Wg, const float* __restrict__ Wn,
    _Float16* __restrict__ wh, _Float16* __restrict__ wl)
{
    const int t    = blockIdx.x * 256 + threadIdx.x;   // 0..32767
    const int grp  = t >> 6;                           // kc*8 + cg*2 + cf  (0..511)
    const int lane = t & 63;
    const int kc   = grp >> 3;
    const int cg   = (grp >> 1) & 3;
    const int cf   = grp & 1;
    const int col  = cg * 32 + cf * 16 + (lane & 15);
    const int k0   = kc * 32 + (lane >> 4) * 8;
    const float* src = (col < 64) ? &Wg[(size_t)col * DDIM + k0]
                                  : &Wn[(size_t)(col - 64) * DDIM + k0];
    const float4 v0 = *reinterpret_cast<const float4*>(src);
    const float4 v1 = *reinterpret_cast<const float4*>(src + 4);
    float vv[8] = {v0.x, v0.y, v0.z, v0.w, v1.x, v1.y, v1.z, v1.w};
    union { _Float16 h[8]; uint4 u; } hh, ll;
    #pragma unroll
    for (int j = 0; j < 8; ++j) {
        hh.h[j] = (_Float16)vv[j];
        ll.h[j] = (_Float16)((vv[j] - (float)hh.h[j]) * 2048.0f);
    }
    const size_t off = (size_t)grp * 512 + lane * 8;
    *reinterpret_cast<uint4*>(&wh[off]) = hh.u;
    *reinterpret_cast<uint4*>(&wl[off]) = ll.u;
}

__device__ __forceinline__ void split8(const float4 a, const float4 b, f16x8& h, f16x8& l) {
    const float v[8] = {a.x, a.y, a.z, a.w, b.x, b.y, b.z, b.w};
    #pragma unroll
    for (int j = 0; j < 8; ++j) {
        const _Float16 hh = (_Float16)v[j];
        h[j] = hh;
        l[j] = (_Float16)((v[j] - (float)hh) * 2048.0f);
    }
}

// ---------- kernel 2: partial GEMM (64 rows x 128 cols x K=1024 per block) ----------
__global__ __launch_bounds__(512, 2) void gemm_part_kernel(
    const float* __restrict__ x,
    const _Float16* __restrict__ whp,
    const _Float16* __restrict__ wlp,
    float* __restrict__ pbuf)
{
    extern __shared__ __align__(16) unsigned char smem[];   // NBUF*BUFSZ = 72KB

    const int tid  = threadIdx.x;
    const int lane = tid & 63;
    const int wid  = tid >> 6;            // 0..7
    const int rg   = wid >> 2;            // row-group 0..1 (32 rows each)
    const int cg   = wid & 3;             // col-group 0..3 (32 cols each)
    const int g    = (lane >> 4) & 3;
    const int idx  = lane & 15;
    const int kh   = blockIdx.x >> 8;     // K-half 0..1
    const int rt   = blockIdx.x & 255;    // row-tile 0..255
    const int row_base = rt * BM;

    // ---- staging addresses (thread stages 48B/iter: x, Bh, Bl) ----
    const int sr  = tid >> 3;             // 0..63
    const int sq  = tid & 7;
    const int sq2 = sq ^ (sr & 7);        // pre-swizzled source slot
    const float* xsrc = x + (size_t)(row_base + sr) * DDIM + kh * 1024 + sq2 * 4;
    const char* bh2 = (const char*)whp + (size_t)kh * 262144 + tid * 16;
    const char* bl2 = (const char*)wlp + (size_t)kh * 262144 + tid * 16;

    // ---- A-frag read offsets (swizzled): row = rg*32 + rf*16 + idx ----
    int aoff[2][2];
    #pragma unroll
    for (int rf = 0; rf < 2; ++rf) {
        const int row = rg * 32 + rf * 16 + idx;
        #pragma unroll
        for (int j = 0; j < 2; ++j)
            aoff[rf][j] = row * 128 + (((2 * g + j) ^ (row & 7)) << 4);
    }
    int bhoff[2], bloff[2];
    #pragma unroll
    for (int cf = 0; cf < 2; ++cf) {
        bhoff[cf] = 8192  + (cg * 2 + cf) * 1024 + lane * 16;
        bloff[cf] = 16384 + (cg * 2 + cf) * 1024 + lane * 16;
    }

    f32x4 accm[2][2], accc[2][2];
    #pragma unroll
    for (int rf = 0; rf < 2; ++rf)
        #pragma unroll
        for (int cf = 0; cf < 2; ++cf) { accm[rf][cf] = (f32x4)0.0f; accc[rf][cf] = (f32x4)0.0f; }

    auto stage = [&](int u, int b) {      // 3 DMA ops/thread
        gload16(xsrc + u * 32,            smem + b + tid * 16);
        gload16(bh2 + (size_t)u * 8192,   smem + b + 8192  + tid * 16);
        gload16(bl2 + (size_t)u * 8192,   smem + b + 16384 + tid * 16);
    };

    auto compute = [&](int b) {
        const float4 a00 = *reinterpret_cast<const float4*>(&smem[b + aoff[0][0]]);
        const float4 a01 = *reinterpret_cast<const float4*>(&smem[b + aoff[0][1]]);
        const float4 a10 = *reinterpret_cast<const float4*>(&smem[b + aoff[1][0]]);
        const float4 a11 = *reinterpret_cast<const float4*>(&smem[b + aoff[1][1]]);
        const f16x8 Bh0 = *reinterpret_cast<const f16x8*>(&smem[b + bhoff[0]]);
        const f16x8 Bh1 = *reinterpret_cast<const f16x8*>(&smem[b + bhoff[1]]);
        const f16x8 Bl0 = *reinterpret_cast<const f16x8*>(&smem[b + bloff[0]]);
        const f16x8 Bl1 = *reinterpret_cast<const f16x8*>(&smem[b + bloff[1]]);

        f16x8 Ah0, Al0, Ah1, Al1;
        split8(a00, a01, Ah0, Al0);
        split8(a10, a11, Ah1, Al1);

        accm[0][0] = __builtin_amdgcn_mfma_f32_16x16x32_f16(Ah0, Bh0, accm[0][0], 0, 0, 0);
        accm[0][1] = __builtin_amdgcn_mfma_f32_16x16x32_f16(Ah0, Bh1, accm[0][1], 0, 0, 0);
        accm[1][0] = __builtin_amdgcn_mfma_f32_16x16x32_f16(Ah1, Bh0, accm[1][0], 0, 0, 0);
        accm[1][1] = __builtin_amdgcn_mfma_f32_16x16x32_f16(Ah1, Bh1, accm[1][1], 0, 0, 0);
        accc[0][0] = __builtin_amdgcn_mfma_f32_16x16x32_f16(Al0, Bh0, accc[0][0], 0, 0, 0);
        accc[0][1] = __builtin_amdgcn_mfma_f32_16x16x32_f16(Al0, Bh1, accc[0][1], 0, 0, 0);
        accc[1][0] = __builtin_amdgcn_mfma_f32_16x16x32_f16(Al1, Bh0, accc[1][0], 0, 0, 0);
        accc[1][1] = __builtin_amdgcn_mfma_f32_16x16x32_f16(Al1, Bh1, accc[1][1], 0, 0, 0);
        accc[0][0] = __builtin_amdgcn_mfma_f32_16x16x32_f16(Ah0, Bl0, accc[0][0], 0, 0, 0);
        accc[0][1] = __builtin_amdgcn_mfma_f32_16x16x32_f16(Ah0, Bl1, accc[0][1], 0, 0, 0);
        accc[1][0] = __builtin_amdgcn_mfma_f32_16x16x32_f16(Ah1, Bl0, accc[1][0], 0, 0, 0);
        accc[1][1] = __builtin_amdgcn_mfma_f32_16x16x32_f16(Ah1, Bl1, accc[1][1], 0, 0, 0);
    };

    // ---- prologue: k-steps 0,1 in flight ----
    stage(0, 0);
    stage(1, BUFSZ);

    // ---- main loop: wait vmcnt(3) | barrier | stage(t+2) | compute(t) ----
    int rbase = 0, wbase = 2 * BUFSZ;
    for (int t = 0; t < NKS; ++t) {
        if (t < NKS - 1) {
            asm volatile("s_waitcnt vmcnt(3)" ::: "memory");   // t's 3 landed; t+1's in flight
        } else {
            asm volatile("s_waitcnt vmcnt(0)" ::: "memory");
        }
        __builtin_amdgcn_s_barrier();
        if (t < NKS - 2) stage(t + 2, wbase);   // overwrites buffer consumed at t-1 (barrier-ordered)
        __builtin_amdgcn_sched_barrier(0);
        compute(rbase);
        rbase += BUFSZ; if (rbase == NBUF * BUFSZ) rbase = 0;
        wbase += BUFSZ; if (wbase == NBUF * BUFSZ) wbase = 0;
    }

    // ---- write partial logits (f32), hi+lo combined ----
    float* dst = pbuf + (size_t)kh * NROWS * 128;
    #pragma unroll
    for (int rf = 0; rf < 2; ++rf)
        #pragma unroll
        for (int cf = 0; cf < 2; ++cf) {
            const int col = cg * 32 + cf * 16 + idx;
            #pragma unroll
            for (int q = 0; q < 4; ++q) {
                const int lrow = rg * 32 + rf * 16 + g * 4 + q;
                dst[(size_t)(row_base + lrow) * 128 + col] =
                    accm[rf][cf][q] + accc[rf][cf][q] * 4.8828125e-4f;
            }
        }
}

// ---------- kernel 3: reduce halves + softplus/noise/top-2/softmax ----------
__global__ __launch_bounds__(256) void reduce_topk_kernel(
    const float* __restrict__ pbuf,
    const float* __restrict__ noise,
    float* __restrict__ out)
{
    const int tid = threadIdx.x;
    const int row = tid >> 3;
    const int j   = tid & 7;
    const int e0  = j * 8;
    const int grow = blockIdx.x * 32 + row;

    const float* p0 = pbuf + (size_t)grow * 128;
    const float* p1 = pbuf + (size_t)(NROWS + grow) * 128;

    float4 c0 = *reinterpret_cast<const float4*>(&p0[e0]);
    float4 c1 = *reinterpret_cast<const float4*>(&p0[e0 + 4]);
    float4 s0 = *reinterpret_cast<const float4*>(&p0[64 + e0]);
    float4 s1 = *reinterpret_cast<const float4*>(&p0[64 + e0 + 4]);
    const float4 d0 = *reinterpret_cast<const float4*>(&p1[e0]);
    const float4 d1 = *reinterpret_cast<const float4*>(&p1[e0 + 4]);
    const float4 t0 = *reinterpret_cast<const float4*>(&p1[64 + e0]);
    const float4 t1 = *reinterpret_cast<const float4*>(&p1[64 + e0 + 4]);
    c0.x += d0.x; c0.y += d0.y; c0.z += d0.z; c0.w += d0.w;
    c1.x += d1.x; c1.y += d1.y; c1.z += d1.z; c1.w += d1.w;
    s0.x += t0.x; s0.y += t0.y; s0.z += t0.z; s0.w += t0.w;
    s1.x += t1.x; s1.y += t1.y; s1.z += t1.z; s1.w += t1.w;

    *reinterpret_cast<float4*>(&out[CLEAN_OFF + (size_t)grow * EDIM + e0])     = c0;
    *reinterpret_cast<float4*>(&out[CLEAN_OFF + (size_t)grow * EDIM + e0 + 4]) = c1;

    const float4 z0 = *reinterpret_cast<const float4*>(&noise[(size_t)grow * EDIM + e0]);
    const float4 z1 = *reinterpret_cast<const float4*>(&noise[(size_t)grow * EDIM + e0 + 4]);

    float nv[8];
    nv[0] = fmaf(softplus_f(s0.x), z0.x, c0.x);
    nv[1] = fmaf(softplus_f(s0.y), z0.y, c0.y);
    nv[2] = fmaf(softplus_f(s0.z), z0.z, c0.z);
    nv[3] = fmaf(softplus_f(s0.w), z0.w, c0.w);
    nv[4] = fmaf(softplus_f(s1.x), z1.x, c1.x);
    nv[5] = fmaf(softplus_f(s1.y), z1.y, c1.y);
    nv[6] = fmaf(softplus_f(s1.z), z1.z, c1.z);
    nv[7] = fmaf(softplus_f(s1.w), z1.w, c1.w);

    float v0 = nv[0], v1 = -INFINITY;
    int   i0 = e0,    i1 = -1;
    #pragma unroll
    for (int m = 1; m < 8; ++m) {
        const float v = nv[m]; const int e = e0 + m;
        if (v > v0)      { v1 = v0; i1 = i0; v0 = v; i0 = e; }
        else if (v > v1) { v1 = v;  i1 = e; }
    }
    #pragma unroll
    for (int d = 1; d < 8; d <<= 1) {
        const float ov0 = __shfl_xor(v0, d); const int oi0 = __shfl_xor(i0, d);
        const float ov1 = __shfl_xor(v1, d); const int oi1 = __shfl_xor(i1, d);
        const bool aFirst = (v0 > ov0) || (v0 == ov0 && i0 < oi0);
        float n0, n1; int ni0, ni1;
        if (aFirst) {
            n0 = v0; ni0 = i0;
            const bool s = (v1 > ov0) || (v1 == ov0 && i1 < oi0);
            n1 = s ? v1 : ov0; ni1 = s ? i1 : oi0;
        } else {
            n0 = ov0; ni0 = oi0;
            const bool s = (ov1 > v0) || (ov1 == v0 && oi1 < i0);
            n1 = s ? ov1 : v0; ni1 = s ? oi1 : i0;
        }
        v0 = n0; i0 = ni0; v1 = n1; i1 = ni1;
    }
    if (j == 0) {
        const float ex = expf(v1 - v0);
        const float w0 = 1.0f / (1.0f + ex);
        const float w1 = 1.0f - w0;
        out[(size_t)grow * 2 + 0] = w0;
        out[(size_t)grow * 2 + 1] = w1;
        out[IDX_OFF + (size_t)grow * 2 + 0] = (float)i0;
        out[IDX_OFF + (size_t)grow * 2 + 1] = (float)i1;
    }
}

extern "C" void kernel_launch(void* const* d_in, const int* in_sizes, int n_in,
                              void* d_out, int out_size, void* d_ws, size_t ws_size,
                              hipStream_t stream) {
    const float* x     = (const float*)d_in[0];
    const float* Wg    = (const float*)d_in[1];
    const float* Wn    = (const float*)d_in[2];
    const float* noise = (const float*)d_in[3];
    float* out = (float*)d_out;

    _Float16* wh = (_Float16*)d_ws;
    _Float16* wl = wh + WPACK;                                  // +512KB
    float* pbuf  = (float*)((char*)d_ws + (1 << 20));           // 16MB partials @1MB

    split_w_kernel<<<dim3(128), dim3(256), 0, stream>>>(Wg, Wn, wh, wl);
    gemm_part_kernel<<<dim3(512), dim3(512), NBUF * BUFSZ, stream>>>(x, wh, wl, pbuf);
    reduce_topk_kernel<<<dim3(NROWS / 32), dim3(256), 0, stream>>>(pbuf, noise, out);
}

// Round 15
// 54.569 us; speedup vs baseline: 1.0121x; 1.0121x over previous
//
#include <hip/hip_runtime.h>
#include <math.h>

// NoisyTopKGating via fp16x2-split MFMA. R8 structure + 1-iteration LDS read lookahead:
// at iter t, ds_reads for buf[t+1] issue right after the barrier and overlap the MFMAs
// of iter t (fragments read at t-1). NBUF=5 x 24KB = 120KB (overwrite distance proof:
// buf m overwritten at iter m+2; last reads of m consumed at iter m; barrier(m+1)
// orders them). Prefetch dist 3, vmcnt(6) steady-state, counted tails.
// BM=64 rows/block, 512 threads (8 waves: 2 rg x 4 cg), 256 blocks (1/CU).
// out layout (f32 flat): weights [N,2] @0, indices-as-float [N,2] @32768, clean [N,64] @65536.
// d_ws: Bh packed frags (512KB) @0, Bl packed frags (512KB) @+262144 f16.
// Packed layout (f16 units): [(kc*8 + cg*2 + cf)*512 + lane*8 + j]
//   col = cg*32 + cf*16 + (lane&15),  k = kc*32 + (lane>>4)*8 + j.

constexpr int NROWS = 16384;
constexpr int DDIM  = 2048;
constexpr int EDIM  = 64;
constexpr int BM    = 64;             // rows per block
constexpr int NKS   = 64;             // k-steps of 32
constexpr int LSTR  = 132;            // epilogue LDS stride (floats)
constexpr int IDX_OFF   = NROWS * 2;
constexpr int CLEAN_OFF = NROWS * 4;
constexpr size_t WPACK = 262144;      // f16 elements per packed matrix (128*2048)
constexpr int BUFSZ = 24576;          // X 8KB @0, Bh 8KB @8192, Bl 8KB @16384
constexpr int NBUF  = 5;              // 120KB dynamic LDS
constexpr int LDSSZ = NBUF * BUFSZ;

typedef _Float16 f16x8 __attribute__((ext_vector_type(8)));
typedef float    f32x4 __attribute__((ext_vector_type(4)));

__device__ __forceinline__ float softplus_f(float z) {
    return fmaxf(z, 0.0f) + log1pf(expf(-fabsf(z)));
}

__device__ __forceinline__ void gload16(const void* g, void* l) {
    __builtin_amdgcn_global_load_lds(
        (const __attribute__((address_space(1))) unsigned int*)g,
        (__attribute__((address_space(3))) unsigned int*)l, 16, 0, 0);
}

// ---------- pre-kernel: split + pack weights into frag-ordered hi/lo ----------
__global__ __launch_bounds__(256) void split_w_kernel(
    const float* __restrict__ Wg, const float* __restrict__ Wn,
    _Float16* __restrict__ wh, _Float16* __restrict__ wl)
{
    const int t    = blockIdx.x * 256 + threadIdx.x;   // 0..32767
    const int grp  = t >> 6;                           // kc*8 + cg*2 + cf  (0..511)
    const int lane = t & 63;
    const int kc   = grp >> 3;
    const int cg   = (grp >> 1) & 3;
    const int cf   = grp & 1;
    const int col  = cg * 32 + cf * 16 + (lane & 15);
    const int k0   = kc * 32 + (lane >> 4) * 8;
    const float* src = (col < 64) ? &Wg[(size_t)col * DDIM + k0]
                                  : &Wn[(size_t)(col - 64) * DDIM + k0];
    const float4 v0 = *reinterpret_cast<const float4*>(src);
    const float4 v1 = *reinterpret_cast<const float4*>(src + 4);
    float vv[8] = {v0.x, v0.y, v0.z, v0.w, v1.x, v1.y, v1.z, v1.w};
    union { _Float16 h[8]; uint4 u; } hh, ll;
    #pragma unroll
    for (int j = 0; j < 8; ++j) {
        hh.h[j] = (_Float16)vv[j];
        ll.h[j] = (_Float16)((vv[j] - (float)hh.h[j]) * 2048.0f);
    }
    const size_t off = (size_t)grp * 512 + lane * 8;
    *reinterpret_cast<uint4*>(&wh[off]) = hh.u;
    *reinterpret_cast<uint4*>(&wl[off]) = ll.u;
}

__device__ __forceinline__ void split8(const float4 a, const float4 b, f16x8& h, f16x8& l) {
    const float v[8] = {a.x, a.y, a.z, a.w, b.x, b.y, b.z, b.w};
    #pragma unroll
    for (int j = 0; j < 8; ++j) {
        const _Float16 hh = (_Float16)v[j];
        h[j] = hh;
        l[j] = (_Float16)((v[j] - (float)hh) * 2048.0f);
    }
}

struct Frags {
    float4 a00, a01, a10, a11;
    f16x8  bh0, bh1, bl0, bl1;
};

// ---------- main fused kernel ----------
__global__ __launch_bounds__(512, 1) void gating_mfma_kernel(
    const float* __restrict__ x,
    const float* __restrict__ noise,
    const _Float16* __restrict__ whp,
    const _Float16* __restrict__ wlp,
    float* __restrict__ out)
{
    extern __shared__ __align__(16) unsigned char smem[];   // 120KB

    const int tid = threadIdx.x;
    const int row_base = blockIdx.x * BM;
    const int lane = tid & 63;
    const int wid  = tid >> 6;           // 0..7
    const int g    = (lane >> 4) & 3;    // k-group
    const int idx  = lane & 15;
    const int rg   = wid >> 2;           // row-group 0..1
    const int cg   = wid & 3;            // col-group 0..3

    // ---- staging addresses: thread stages 16B each of X/Bh/Bl; X source pre-swizzled ----
    const int sr  = tid >> 3;            // row 0..63
    const int sq  = tid & 7;             // 16B slot
    const int sq2 = sq ^ (sr & 7);
    const float* xsrc = x + (size_t)(row_base + sr) * DDIM + sq2 * 4;
    const char* bhsrc = (const char*)whp + tid * 16;
    const char* blsrc = (const char*)wlp + tid * 16;

    // ---- A-frag read offsets (swizzled): row = rg*32 + rf*16 + idx ----
    int aoff[2][2];
    #pragma unroll
    for (int rf = 0; rf < 2; ++rf) {
        const int row = rg * 32 + rf * 16 + idx;
        #pragma unroll
        for (int j = 0; j < 2; ++j)
            aoff[rf][j] = row * 128 + (((g * 2 + j) ^ (row & 7)) << 4);
    }
    int bhoff[2], bloff[2];
    #pragma unroll
    for (int cf = 0; cf < 2; ++cf) {
        bhoff[cf] = 8192  + (cg * 2 + cf) * 1024 + lane * 16;
        bloff[cf] = 16384 + (cg * 2 + cf) * 1024 + lane * 16;
    }

    f32x4 accm[2][2], accc[2][2];
    #pragma unroll
    for (int rf = 0; rf < 2; ++rf)
        #pragma unroll
        for (int cf = 0; cf < 2; ++cf) { accm[rf][cf] = (f32x4)0.0f; accc[rf][cf] = (f32x4)0.0f; }

    auto stage = [&](int u, int b) {     // 3 DMA ops/thread
        gload16(xsrc + u * 32,                smem + b + tid * 16);
        gload16(bhsrc + (size_t)u * 8192,     smem + b + 8192  + tid * 16);
        gload16(blsrc + (size_t)u * 8192,     smem + b + 16384 + tid * 16);
    };

    auto readFrags = [&](int b, Frags& f) {
        f.a00 = *reinterpret_cast<const float4*>(&smem[b + aoff[0][0]]);
        f.a01 = *reinterpret_cast<const float4*>(&smem[b + aoff[0][1]]);
        f.a10 = *reinterpret_cast<const float4*>(&smem[b + aoff[1][0]]);
        f.a11 = *reinterpret_cast<const float4*>(&smem[b + aoff[1][1]]);
        f.bh0 = *reinterpret_cast<const f16x8*>(&smem[b + bhoff[0]]);
        f.bh1 = *reinterpret_cast<const f16x8*>(&smem[b + bhoff[1]]);
        f.bl0 = *reinterpret_cast<const f16x8*>(&smem[b + bloff[0]]);
        f.bl1 = *reinterpret_cast<const f16x8*>(&smem[b + bloff[1]]);
    };

    auto computeF = [&](const Frags& f) {
        f16x8 Ah0, Al0, Ah1, Al1;
        split8(f.a00, f.a01, Ah0, Al0);
        split8(f.a10, f.a11, Ah1, Al1);
        accm[0][0] = __builtin_amdgcn_mfma_f32_16x16x32_f16(Ah0, f.bh0, accm[0][0], 0, 0, 0);
        accm[0][1] = __builtin_amdgcn_mfma_f32_16x16x32_f16(Ah0, f.bh1, accm[0][1], 0, 0, 0);
        accm[1][0] = __builtin_amdgcn_mfma_f32_16x16x32_f16(Ah1, f.bh0, accm[1][0], 0, 0, 0);
        accm[1][1] = __builtin_amdgcn_mfma_f32_16x16x32_f16(Ah1, f.bh1, accm[1][1], 0, 0, 0);
        accc[0][0] = __builtin_amdgcn_mfma_f32_16x16x32_f16(Al0, f.bh0, accc[0][0], 0, 0, 0);
        accc[0][1] = __builtin_amdgcn_mfma_f32_16x16x32_f16(Al0, f.bh1, accc[0][1], 0, 0, 0);
        accc[1][0] = __builtin_amdgcn_mfma_f32_16x16x32_f16(Al1, f.bh0, accc[1][0], 0, 0, 0);
        accc[1][1] = __builtin_amdgcn_mfma_f32_16x16x32_f16(Al1, f.bh1, accc[1][1], 0, 0, 0);
        accc[0][0] = __builtin_amdgcn_mfma_f32_16x16x32_f16(Ah0, f.bl0, accc[0][0], 0, 0, 0);
        accc[0][1] = __builtin_amdgcn_mfma_f32_16x16x32_f16(Ah0, f.bl1, accc[0][1], 0, 0, 0);
        accc[1][0] = __builtin_amdgcn_mfma_f32_16x16x32_f16(Ah1, f.bl0, accc[1][0], 0, 0, 0);
        accc[1][1] = __builtin_amdgcn_mfma_f32_16x16x32_f16(Ah1, f.bl1, accc[1][1], 0, 0, 0);
    };

    Frags f0, f1;

    // ---- prologue: buffers 0..2 in flight; read buf0 into f0 ----
    stage(0, 0);
    stage(1, BUFSZ);
    stage(2, 2 * BUFSZ);
    asm volatile("s_waitcnt vmcnt(6)" ::: "memory");   // buf0 landed (this wave's slice; barrier covers all)
    __builtin_amdgcn_s_barrier();
    __builtin_amdgcn_sched_barrier(0);
    readFrags(0, f0);

    // ---- main loop: t = 0..59 in parity pairs ----
    // Body(t): stage(t+3) | vmcnt(6) [buf t+1 landed] | barrier | read buf[t+1] | MFMA(t)
    int wb = 3 * BUFSZ;      // write offset for stage(t+3)
    int rb = 1 * BUFSZ;      // read offset for buf[t+1]
    for (int tt = 0; tt < 30; ++tt) {
        // even t: consume f0, read into f1
        stage(2 * tt + 3, wb);
        wb += BUFSZ; if (wb == LDSSZ) wb = 0;
        asm volatile("s_waitcnt vmcnt(6)" ::: "memory");
        __builtin_amdgcn_s_barrier();
        __builtin_amdgcn_sched_barrier(0);
        readFrags(rb, f1);
        rb += BUFSZ; if (rb == LDSSZ) rb = 0;
        computeF(f0);
        // odd t: consume f1, read into f0
        stage(2 * tt + 4, wb);
        wb += BUFSZ; if (wb == LDSSZ) wb = 0;
        asm volatile("s_waitcnt vmcnt(6)" ::: "memory");
        __builtin_amdgcn_s_barrier();
        __builtin_amdgcn_sched_barrier(0);
        readFrags(rb, f0);
        rb += BUFSZ; if (rb == LDSSZ) rb = 0;
        computeF(f1);
    }
    // ---- t=60: stage(63); vmcnt(6); read buf61 -> f1; compute f0 ----
    stage(63, wb);
    asm volatile("s_waitcnt vmcnt(6)" ::: "memory");
    __builtin_amdgcn_s_barrier();
    __builtin_amdgcn_sched_barrier(0);
    readFrags(rb, f1);                   // rb = buf61
    rb += BUFSZ; if (rb == LDSSZ) rb = 0;
    computeF(f0);
    // ---- t=61: vmcnt(3); read buf62 -> f0; compute f1 ----
    asm volatile("s_waitcnt vmcnt(3)" ::: "memory");
    __builtin_amdgcn_s_barrier();
    __builtin_amdgcn_sched_barrier(0);
    readFrags(rb, f0);                   // rb = buf62
    rb += BUFSZ; if (rb == LDSSZ) rb = 0;
    computeF(f1);
    // ---- t=62: vmcnt(0); read buf63 -> f1; compute f0 ----
    asm volatile("s_waitcnt vmcnt(0)" ::: "memory");
    __builtin_amdgcn_s_barrier();
    __builtin_amdgcn_sched_barrier(0);
    readFrags(rb, f1);                   // rb = buf63
    computeF(f0);
    // ---- t=63: compute f1 (all reads done) ----
    computeF(f1);

    __builtin_amdgcn_s_barrier();        // all ds_reads done before epilogue reuse

    // ---- epilogue: logits -> LDS [64][132] f32 ----
    float* L = reinterpret_cast<float*>(smem);
    #pragma unroll
    for (int rf = 0; rf < 2; ++rf)
        #pragma unroll
        for (int cf = 0; cf < 2; ++cf) {
            const int col = cg * 32 + cf * 16 + idx;
            #pragma unroll
            for (int q = 0; q < 4; ++q) {
                const int lrow = rg * 32 + rf * 16 + g * 4 + q;
                L[lrow * LSTR + col] = accm[rf][cf][q] + accc[rf][cf][q] * 4.8828125e-4f;
            }
        }
    __syncthreads();

    // ---- fused softplus/noise/top-2/softmax: 8 threads per row, 64 rows ----
    {
        const int row = tid >> 3;
        const int j   = tid & 7;
        const int e0  = j * 8;
        const int grow = row_base + row;

        const float4 c0 = *reinterpret_cast<const float4*>(&L[row * LSTR + e0]);
        const float4 c1 = *reinterpret_cast<const float4*>(&L[row * LSTR + e0 + 4]);
        const float4 s0 = *reinterpret_cast<const float4*>(&L[row * LSTR + 64 + e0]);
        const float4 s1 = *reinterpret_cast<const float4*>(&L[row * LSTR + 64 + e0 + 4]);
        *reinterpret_cast<float4*>(&out[CLEAN_OFF + (size_t)grow * EDIM + e0])     = c0;
        *reinterpret_cast<float4*>(&out[CLEAN_OFF + (size_t)grow * EDIM + e0 + 4]) = c1;

        const float4 z0 = *reinterpret_cast<const float4*>(&noise[(size_t)grow * EDIM + e0]);
        const float4 z1 = *reinterpret_cast<const float4*>(&noise[(size_t)grow * EDIM + e0 + 4]);

        float nv[8];
        nv[0] = fmaf(softplus_f(s0.x), z0.x, c0.x);
        nv[1] = fmaf(softplus_f(s0.y), z0.y, c0.y);
        nv[2] = fmaf(softplus_f(s0.z), z0.z, c0.z);
        nv[3] = fmaf(softplus_f(s0.w), z0.w, c0.w);
        nv[4] = fmaf(softplus_f(s1.x), z1.x, c1.x);
        nv[5] = fmaf(softplus_f(s1.y), z1.y, c1.y);
        nv[6] = fmaf(softplus_f(s1.z), z1.z, c1.z);
        nv[7] = fmaf(softplus_f(s1.w), z1.w, c1.w);

        float v0 = nv[0], v1 = -INFINITY;
        int   i0 = e0,    i1 = -1;
        #pragma unroll
        for (int m = 1; m < 8; ++m) {
            const float v = nv[m]; const int e = e0 + m;
            if (v > v0)      { v1 = v0; i1 = i0; v0 = v; i0 = e; }
            else if (v > v1) { v1 = v;  i1 = e; }
        }
        #pragma unroll
        for (int d = 1; d < 8; d <<= 1) {
            const float ov0 = __shfl_xor(v0, d); const int oi0 = __shfl_xor(i0, d);
            const float ov1 = __shfl_xor(v1, d); const int oi1 = __shfl_xor(i1, d);
            const bool aFirst = (v0 > ov0) || (v0 == ov0 && i0 < oi0);
            float n0, n1; int ni0, ni1;
            if (aFirst) {
                n0 = v0; ni0 = i0;
                const bool s = (v1 > ov0) || (v1 == ov0 && i1 < oi0);
                n1 = s ? v1 : ov0; ni1 = s ? i1 : oi0;
            } else {
                n0 = ov0; ni0 = oi0;
                const bool s = (ov1 > v0) || (ov1 == v0 && oi1 < i0);
                n1 = s ? ov1 : v0; ni1 = s ? oi1 : i0;
            }
            v0 = n0; i0 = ni0; v1 = n1; i1 = ni1;
        }
        if (j == 0) {
            const float ex = expf(v1 - v0);
            const float w0 = 1.0f / (1.0f + ex);
            const float w1 = 1.0f - w0;
            out[(size_t)grow * 2 + 0] = w0;
            out[(size_t)grow * 2 + 1] = w1;
            out[IDX_OFF + (size_t)grow * 2 + 0] = (float)i0;
            out[IDX_OFF + (size_t)grow * 2 + 1] = (float)i1;
        }
    }
}

extern "C" void kernel_launch(void* const* d_in, const int* in_sizes, int n_in,
                              void* d_out, int out_size, void* d_ws, size_t ws_size,
                              hipStream_t stream) {
    const float* x     = (const float*)d_in[0];
    const float* Wg    = (const float*)d_in[1];
    const float* Wn    = (const float*)d_in[2];
    const float* noise = (const float*)d_in[3];
    float* out = (float*)d_out;

    _Float16* wh = (_Float16*)d_ws;
    _Float16* wl = wh + WPACK;               // packed matrix is 262144 f16 (512KB)

    split_w_kernel<<<dim3(128), dim3(256), 0, stream>>>(Wg, Wn, wh, wl);
    gating_mfma_kernel<<<dim3(NROWS / BM), dim3(512), LDSSZ, stream>>>(x, noise, wh, wl, out);
}